// Round 12
// baseline (620.668 us; speedup 1.0000x reference)
//
#include <hip/hip_runtime.h>

// MinkowskiBroadcast: out[p][c] = x_glob[batch_idx[p]][c]
//
// R10 post-mortem: pipeline+LDS moved bench only 536->516 us, and for the
// 3rd time the kernel's own dispatch is ABSENT from rocprof top-5
// (cutoff ~325 us) -> kernel runs <325 us while bench says 516.
// Model: dur_us = C (harness re-poison fills ~400 us inside timed window)
//              + T (kernel).
// THIS ROUND = MEASUREMENT: launch the identical kernel TWICE (idempotent,
// same values rewritten; async on stream; graph-safe). dur_us becomes
// C + 2T, so T = dur_us - 516.1 from R10.
//   branch A: T ~ 95-115  -> kernel near 84us write-BW floor -> roofline.
//   branch B: T ~ 180-220 -> real headroom; optimize with T observable.

typedef float v4f __attribute__((ext_vector_type(4)));

#define BATCH 8

__global__ __launch_bounds__(256) void
minkowski_broadcast_kernel(const v4f* __restrict__ xg,   // [32*32] 16B quads
                           const int* __restrict__ bidx, // [N]
                           v4f*       __restrict__ out,  // [N*32]
                           int n_chunks) {
    __shared__ v4f lds_xg[32 * 32];   // 16 KB: whole x_glob table
    for (int i = threadIdx.x; i < 32 * 32; i += 256)
        lds_xg[i] = xg[i];
    __syncthreads();

    const int tid    = (int)(blockIdx.x * blockDim.x + threadIdx.x);
    const int stride = (int)(gridDim.x * blockDim.x);

    int b[BATCH];
#pragma unroll
    for (int k = 0; k < BATCH; ++k) {
        int g = tid + k * stride;
        b[k] = (g < n_chunks) ? bidx[g >> 5] : 0;
    }

    for (int base = tid; base < n_chunks; base += BATCH * stride) {
        int bn[BATCH];
        const int nbase = base + BATCH * stride;
#pragma unroll
        for (int k = 0; k < BATCH; ++k) {
            int g = nbase + k * stride;
            bn[k] = (g < n_chunks) ? bidx[g >> 5] : 0;
        }
#pragma unroll
        for (int k = 0; k < BATCH; ++k) {
            int g = base + k * stride;
            if (g < n_chunks)
                out[g] = lds_xg[(b[k] << 5) + (g & 31)];
        }
#pragma unroll
        for (int k = 0; k < BATCH; ++k) b[k] = bn[k];
    }
}

extern "C" void kernel_launch(void* const* d_in, const int* in_sizes, int n_in,
                              void* d_out, int out_size, void* d_ws, size_t ws_size,
                              hipStream_t stream) {
    const v4f* xg   = (const v4f*)d_in[0];  // x_glob [32][128] f32
    const int* bidx = (const int*)d_in[1];  // batch_idx [N] i32
    v4f*       out  = (v4f*)d_out;          // [N][128] f32

    const int n_chunks = out_size / 4;      // 16B chunks (N * 128 / 4)

    const int block = 256;
    const int grid  = 2048;
    // MEASUREMENT: two identical idempotent launches -> dur_us = C + 2T.
    minkowski_broadcast_kernel<<<grid, block, 0, stream>>>(xg, bidx, out, n_chunks);
    minkowski_broadcast_kernel<<<grid, block, 0, stream>>>(xg, bidx, out, n_chunks);
}